// Round 3
// baseline (4311.172 us; speedup 1.0000x reference)
//
#include <hip/hip_runtime.h>

// ApsMultiheadAttention: E=1024 H=16 D=64 L=S=2048 N=2, fp32 throughout.
// Outputs: context (L,N,E) then att (N,L,S), concatenated in d_out.
//
// Round 2 -> 3 change: attn rewritten LDS-resident. Per block: (n, 8 q-rows),
// heads looped inside; logits in registers; p in a 64KB LDS tile; K/V staged
// through a shared 64KB LDS buffer with register prefetch (T14); att
// accumulated in registers across heads, written once. Kills the 4.4GB global
// scratch round-trip measured in round 2 (attn was 3.5ms = pure HBM traffic).

#define EDIM   1024
#define HNUM   16
#define DDIM   64
#define LQ     2048
#define SK     2048
#define NBATCH 2

#define NEG_BIG (-3.0e38f)

// attn tiling
#define RB  8          // q-rows per block
#define ST  256        // s-tile staged in LDS
#define NT  (SK/ST)    // 8 tiles

__device__ __forceinline__ float wave_max_f(float v) {
#pragma unroll
  for (int o = 32; o > 0; o >>= 1) v = fmaxf(v, __shfl_xor(v, o));
  return v;
}
__device__ __forceinline__ float wave_sum_f(float v) {
#pragma unroll
  for (int o = 32; o > 0; o >>= 1) v += __shfl_xor(v, o);
  return v;
}

// ---------------------------------------------------------------------------
// GEMM: C = A(MxK) @ W(NcxK)^T + bias.  Tile 128x128, BK=16, 256 threads,
// 8x8 micro-tile as 2x2 quadrants of 4x4. EPI: 0 plain row-major;
// 1 scatter (N,H,R,D); 2 scatter (N,H,D,R). Rows are (row,n), n fastest.
// (unchanged from round 2 — validated)
template <int EPI>
__global__ __launch_bounds__(256) void gemm_k(
    const float* __restrict__ A, const float* __restrict__ W,
    const float* __restrict__ bias, float* __restrict__ C,
    const int M, const int K, const int Nc, const int R)
{
  __shared__ float As[16][132];
  __shared__ float Bs[16][132];
  const int t  = threadIdx.x;
  const int m0 = blockIdx.y * 128;
  const int n0 = blockIdx.x * 128;
  const int lr = t >> 2;
  const int lk = (t & 3) << 2;
  const int tx = t & 15;
  const int ty = t >> 4;

  float acc[2][2][4][4];
#pragma unroll
  for (int a = 0; a < 2; ++a)
#pragma unroll
    for (int b = 0; b < 2; ++b)
#pragma unroll
      for (int i = 0; i < 4; ++i)
#pragma unroll
        for (int j = 0; j < 4; ++j) acc[a][b][i][j] = 0.f;

  float4 ra0, ra1, rb0, rb1;
  ra0 = *(const float4*)&A[(size_t)(m0 + lr) * K + lk];
  ra1 = *(const float4*)&A[(size_t)(m0 + lr + 64) * K + lk];
  rb0 = *(const float4*)&W[(size_t)(n0 + lr) * K + lk];
  rb1 = *(const float4*)&W[(size_t)(n0 + lr + 64) * K + lk];

  for (int k0 = 0; k0 < K; k0 += 16) {
    __syncthreads();
    As[lk+0][lr]    = ra0.x; As[lk+1][lr]    = ra0.y; As[lk+2][lr]    = ra0.z; As[lk+3][lr]    = ra0.w;
    As[lk+0][lr+64] = ra1.x; As[lk+1][lr+64] = ra1.y; As[lk+2][lr+64] = ra1.z; As[lk+3][lr+64] = ra1.w;
    Bs[lk+0][lr]    = rb0.x; Bs[lk+1][lr]    = rb0.y; Bs[lk+2][lr]    = rb0.z; Bs[lk+3][lr]    = rb0.w;
    Bs[lk+0][lr+64] = rb1.x; Bs[lk+1][lr+64] = rb1.y; Bs[lk+2][lr+64] = rb1.z; Bs[lk+3][lr+64] = rb1.w;
    __syncthreads();
    const int kn = k0 + 16;
    if (kn < K) {
      ra0 = *(const float4*)&A[(size_t)(m0 + lr) * K + kn + lk];
      ra1 = *(const float4*)&A[(size_t)(m0 + lr + 64) * K + kn + lk];
      rb0 = *(const float4*)&W[(size_t)(n0 + lr) * K + kn + lk];
      rb1 = *(const float4*)&W[(size_t)(n0 + lr + 64) * K + kn + lk];
    }
#pragma unroll
    for (int kk = 0; kk < 16; ++kk) {
      const float4 a0 = *(const float4*)&As[kk][ty * 4];
      const float4 a1 = *(const float4*)&As[kk][ty * 4 + 64];
      const float4 b0 = *(const float4*)&Bs[kk][tx * 4];
      const float4 b1 = *(const float4*)&Bs[kk][tx * 4 + 64];
      const float av[2][4] = {{a0.x,a0.y,a0.z,a0.w},{a1.x,a1.y,a1.z,a1.w}};
      const float bv[2][4] = {{b0.x,b0.y,b0.z,b0.w},{b1.x,b1.y,b1.z,b1.w}};
#pragma unroll
      for (int qi = 0; qi < 2; ++qi)
#pragma unroll
        for (int i = 0; i < 4; ++i)
#pragma unroll
          for (int qj = 0; qj < 2; ++qj)
#pragma unroll
            for (int j = 0; j < 4; ++j)
              acc[qi][qj][i][j] = fmaf(av[qi][i], bv[qj][j], acc[qi][qj][i][j]);
    }
  }

#pragma unroll
  for (int qi = 0; qi < 2; ++qi)
#pragma unroll
    for (int i = 0; i < 4; ++i) {
      const int gr = m0 + qi * 64 + ty * 4 + i;
      const int row = gr / NBATCH;
      const int nb  = gr % NBATCH;
#pragma unroll
      for (int qj = 0; qj < 2; ++qj)
#pragma unroll
        for (int j = 0; j < 4; ++j) {
          const int gc = n0 + qj * 64 + tx * 4 + j;
          const float val = acc[qi][qj][i][j] + bias[gc];
          if constexpr (EPI == 0) {
            C[(size_t)gr * Nc + gc] = val;
          } else {
            const int h = gc >> 6, d = gc & 63;
            if constexpr (EPI == 1)
              C[(((size_t)nb * HNUM + h) * R + row) * DDIM + d] = val;
            else
              C[(((size_t)nb * HNUM + h) * DDIM + d) * (size_t)R + row] = val;
          }
        }
    }
}

// ---------------------------------------------------------------------------
// attn: grid = N*(L/RB) = 512 blocks, 1024 threads (16 waves, 4/SIMD).
// Dynamic LDS (138.2 KB): p[8][2048] | kv[16384] (K tiles then V tiles) |
// q[512] | part[4][8][64] | red[16][2] | m[8] | rinv[8].
//
// Thread maps:
//  A1/A2/att: rows {rr, rr+4} (rr=t>>8), col cc=t&255; slots s=j*256+cc.
//  B2 (PV):   rows {rr, rr+4}, d=t&63, s-quarter sq=(t>>6)&3.
__global__ __launch_bounds__(1024, 4) void attn_k(
    const float* __restrict__ qs, const float* __restrict__ kts,
    const float* __restrict__ vs, const float* __restrict__ amask,
    const unsigned char* __restrict__ kpm,
    float* __restrict__ ctx, float* __restrict__ att)
{
  extern __shared__ float lds[];
  float* p_lds = lds;                    // 16384 f
  float* kv    = lds + RB * SK;          // 16384 f
  float* q_lds = kv + 16384;             // 512 f
  float* part  = q_lds + 512;            // 2048 f
  float* red   = part + 2048;            // 32 f
  float* m_l   = red + 32;               // 8 f
  float* ri_l  = m_l + 8;                // 8 f

  const int t    = threadIdx.x;
  const int wg   = blockIdx.x;
  const int n    = wg >> 8;
  const int l0   = (wg & 255) * RB;
  const int wid  = t >> 6;
  const int lane = t & 63;
  const int rr   = t >> 8;        // 0..3 ; rows rr, rr+4
  const int cc   = t & 255;       // A1/A2 col within tile
  const int dd   = t & 63;        // B2 d
  const int sq   = (t >> 6) & 3;  // B2 s-quarter

  float attacc[2][NT];
#pragma unroll
  for (int a = 0; a < 2; ++a)
#pragma unroll
    for (int j = 0; j < NT; ++j) attacc[a][j] = 0.f;

  float4 st4[4];

  for (int h = 0; h < HNUM; ++h) {
    const int nh = n * HNUM + h;
    const float* ktb = kts + (size_t)nh * DDIM * SK;
    const float* vb  = vs  + (size_t)nh * SK * DDIM;

    // ---- stage K tile 0 + Q (loads before barrier: latency hidden) ----
#pragma unroll
    for (int kk = 0; kk < 4; ++kk) {
      const int i4 = t + kk * 1024;
      st4[kk] = *(const float4*)&ktb[(size_t)(i4 >> 6) * SK + ((i4 & 63) << 2)];
    }
    float4 qv4;
    if (t < 128) qv4 = ((const float4*)(qs + ((size_t)nh * LQ + l0) * DDIM))[t];
    __syncthreads();  // prev head fully done with kv/part
#pragma unroll
    for (int kk = 0; kk < 4; ++kk) ((float4*)kv)[t + kk * 1024] = st4[kk];
    if (t < 128) ((float4*)q_lds)[t] = qv4;
    __syncthreads();

    // ---- A1: logits (regs) + row max. kv = K tile [d][s] ----
    float lg[2][NT];
    float rmax0 = NEG_BIG, rmax1 = NEG_BIG;
    const float* qrow0 = q_lds + rr * DDIM;
    const float* qrow1 = q_lds + (rr + 4) * DDIM;

    for (int j = 0; j < NT; ++j) {
      if (j < NT - 1) {  // prefetch next K tile into regs
#pragma unroll
        for (int kk = 0; kk < 4; ++kk) {
          const int i4 = t + kk * 1024;
          st4[kk] = *(const float4*)&ktb[(size_t)(i4 >> 6) * SK + (j + 1) * ST + ((i4 & 63) << 2)];
        }
      }
      float a0 = 0.f, b0 = 0.f, a1 = 0.f, b1 = 0.f;
#pragma unroll
      for (int d4 = 0; d4 < DDIM; d4 += 4) {
        const float4 q0 = *(const float4*)&qrow0[d4];
        const float4 q1 = *(const float4*)&qrow1[d4];
        const float k0 = kv[(d4 + 0) * ST + cc];
        const float k1 = kv[(d4 + 1) * ST + cc];
        const float k2 = kv[(d4 + 2) * ST + cc];
        const float k3 = kv[(d4 + 3) * ST + cc];
        a0 = fmaf(q0.x, k0, a0); b0 = fmaf(q0.y, k1, b0);
        a0 = fmaf(q0.z, k2, a0); b0 = fmaf(q0.w, k3, b0);
        a1 = fmaf(q1.x, k0, a1); b1 = fmaf(q1.y, k1, b1);
        a1 = fmaf(q1.z, k2, a1); b1 = fmaf(q1.w, k3, b1);
      }
      const int s = j * ST + cc;
      const bool kill = (kpm[n * SK + s] != 0);
      float l0v = (a0 + b0) * 0.125f + amask[(size_t)(l0 + rr) * SK + s];
      float l1v = (a1 + b1) * 0.125f + amask[(size_t)(l0 + rr + 4) * SK + s];
      if (kill) { l0v = NEG_BIG; l1v = NEG_BIG; }
      lg[0][j] = l0v; lg[1][j] = l1v;
      rmax0 = fmaxf(rmax0, l0v); rmax1 = fmaxf(rmax1, l1v);
      __syncthreads();  // all reads of kv tile j done
      if (j < NT - 1) {
#pragma unroll
        for (int kk = 0; kk < 4; ++kk) ((float4*)kv)[t + kk * 1024] = st4[kk];
        __syncthreads();
      }
    }

    // row max: wave w covers rows (w>>2) and (w>>2)+4
    rmax0 = wave_max_f(rmax0); rmax1 = wave_max_f(rmax1);
    if (lane == 0) { red[wid * 2] = rmax0; red[wid * 2 + 1] = rmax1; }
    __syncthreads();
    if (t < RB) {
      const int g = t & 3, ix = t >> 2;
      float m = red[(4 * g) * 2 + ix];
#pragma unroll
      for (int w = 1; w < 4; ++w) m = fmaxf(m, red[(4 * g + w) * 2 + ix]);
      m_l[t] = m;
    }
    __syncthreads();

    // ---- A2: p = exp(lg - m) -> p_lds + regs; row sums -> rinv ----
    const float mm0 = m_l[rr], mm1 = m_l[rr + 4];
    float sum0 = 0.f, sum1 = 0.f;
#pragma unroll
    for (int j = 0; j < NT; ++j) {
      const float p0 = __expf(lg[0][j] - mm0);
      const float p1 = __expf(lg[1][j] - mm1);
      lg[0][j] = p0; lg[1][j] = p1;         // reuse regs as p
      sum0 += p0; sum1 += p1;
      p_lds[rr * SK + j * ST + cc]       = p0;
      p_lds[(rr + 4) * SK + j * ST + cc] = p1;
    }
    sum0 = wave_sum_f(sum0); sum1 = wave_sum_f(sum1);
    if (lane == 0) { red[wid * 2] = sum0; red[wid * 2 + 1] = sum1; }
    __syncthreads();
    if (t < RB) {
      const int g = t & 3, ix = t >> 2;
      float ssum = 0.f;
#pragma unroll
      for (int w = 0; w < 4; ++w) ssum += red[(4 * g + w) * 2 + ix];
      ri_l[t] = 1.0f / ssum;
    }
    __syncthreads();
    const float ri0 = ri_l[rr], ri1 = ri_l[rr + 4];
#pragma unroll
    for (int j = 0; j < NT; ++j) {
      attacc[0][j] = fmaf(lg[0][j], ri0, attacc[0][j]);
      attacc[1][j] = fmaf(lg[1][j], ri1, attacc[1][j]);
    }

    // ---- B2: PV. kv reused as V tile [s][d] ----
#pragma unroll
    for (int kk = 0; kk < 4; ++kk) {
      const int i4 = t + kk * 1024;
      st4[kk] = *(const float4*)&vb[(size_t)(i4 >> 4) * DDIM + ((i4 & 15) << 2)];
    }
    // kv readers (A1) are all past barriers; safe to overwrite
#pragma unroll
    for (int kk = 0; kk < 4; ++kk) ((float4*)kv)[t + kk * 1024] = st4[kk];
    __syncthreads();

    float ca00 = 0.f, ca01 = 0.f, ca10 = 0.f, ca11 = 0.f;
    for (int j = 0; j < NT; ++j) {
      if (j < NT - 1) {  // prefetch next V tile
#pragma unroll
        for (int kk = 0; kk < 4; ++kk) {
          const int i4 = t + kk * 1024;
          st4[kk] = *(const float4*)&vb[(size_t)((j + 1) * ST + (i4 >> 4)) * DDIM + ((i4 & 15) << 2)];
        }
      }
      const int sb = sq * 64;
      const float* p0r = p_lds + rr * SK + j * ST + sb;
      const float* p1r = p_lds + (rr + 4) * SK + j * ST + sb;
#pragma unroll
      for (int s2 = 0; s2 < 64; s2 += 4) {
        const float4 p0 = *(const float4*)&p0r[s2];   // wave-uniform broadcast
        const float4 p1 = *(const float4*)&p1r[s2];
        const float v0 = kv[(sb + s2 + 0) * DDIM + dd];
        const float v1 = kv[(sb + s2 + 1) * DDIM + dd];
        const float v2 = kv[(sb + s2 + 2) * DDIM + dd];
        const float v3 = kv[(sb + s2 + 3) * DDIM + dd];
        ca00 = fmaf(p0.x, v0, ca00); ca01 = fmaf(p0.y, v1, ca01);
        ca00 = fmaf(p0.z, v2, ca00); ca01 = fmaf(p0.w, v3, ca01);
        ca10 = fmaf(p1.x, v0, ca10); ca11 = fmaf(p1.y, v1, ca11);
        ca10 = fmaf(p1.z, v2, ca10); ca11 = fmaf(p1.w, v3, ca11);
      }
      __syncthreads();
      if (j < NT - 1) {
#pragma unroll
        for (int kk = 0; kk < 4; ++kk) ((float4*)kv)[t + kk * 1024] = st4[kk];
        __syncthreads();
      }
    }
    part[(sq * RB + rr) * DDIM + dd]     = ca00 + ca01;
    part[(sq * RB + rr + 4) * DDIM + dd] = ca10 + ca11;
    __syncthreads();
    if (t < RB * DDIM) {  // 512 threads write ctx
      const int r = t >> 6, d = t & 63;
      float sv = 0.f;
#pragma unroll
      for (int q2 = 0; q2 < 4; ++q2) sv += part[(q2 * RB + r) * DDIM + d];
      ctx[((size_t)(l0 + r) * NBATCH + n) * EDIM + h * DDIM + d] = sv * ri_l[r];
    }
    // next head's first barrier protects part/kv reuse
  }

  // ---- final att write (one pass) ----
  const float c16 = 1.0f / (float)HNUM;
#pragma unroll
  for (int j = 0; j < NT; ++j) {
    att[((size_t)n * LQ + l0 + rr) * SK + j * ST + cc]     = attacc[0][j] * c16;
    att[((size_t)n * LQ + l0 + rr + 4) * SK + j * ST + cc] = attacc[1][j] * c16;
  }
}

// ---------------------------------------------------------------------------
extern "C" void kernel_launch(void* const* d_in, const int* in_sizes, int n_in,
                              void* d_out, int out_size, void* d_ws, size_t ws_size,
                              hipStream_t stream)
{
  const float*         query = (const float*)d_in[0];
  const float*         key   = (const float*)d_in[1];
  const float*         value = (const float*)d_in[2];
  const unsigned char* kpm   = (const unsigned char*)d_in[3];
  const float*         amask = (const float*)d_in[4];
  const float*         ipw   = (const float*)d_in[5];
  const float*         ipb   = (const float*)d_in[6];
  const float*         outw  = (const float*)d_in[7];
  const float*         outb  = (const float*)d_in[8];

  float* outp = (float*)d_out;                          // context (L,N,E)
  float* att  = outp + (size_t)LQ * NBATCH * EDIM;      // att (N,L,S)

  // workspace: q_s 16MB | kt_s 16MB | v_s 16MB | ctx 16MB
  const size_t nQ = (size_t)NBATCH * HNUM * LQ * DDIM;
  const size_t needed = (3 * nQ + (size_t)LQ * NBATCH * EDIM) * 4;
  if (ws_size < needed) return;

  float* ws   = (float*)d_ws;
  float* q_s  = ws;
  float* kt_s = q_s  + nQ;
  float* v_s  = kt_s + nQ;
  float* ctx  = v_s  + nQ;

  const int M = LQ * NBATCH;
  dim3 gg(EDIM / 128, M / 128);

  const int lds_bytes = (RB * SK + 16384 + 512 + 2048 + 32 + 8 + 8) * 4;  // 141504
  (void)hipFuncSetAttribute((const void*)attn_k,
                            hipFuncAttributeMaxDynamicSharedMemorySize, lds_bytes);

  gemm_k<1><<<gg, 256, 0, stream>>>(query, ipw,                   ipb,            q_s,  M, EDIM, EDIM, LQ);
  gemm_k<2><<<gg, 256, 0, stream>>>(key,   ipw + EDIM * EDIM,     ipb + EDIM,     kt_s, M, EDIM, EDIM, SK);
  gemm_k<1><<<gg, 256, 0, stream>>>(value, ipw + 2 * EDIM * EDIM, ipb + 2 * EDIM, v_s,  M, EDIM, EDIM, SK);
  attn_k<<<NBATCH * (LQ / RB), 1024, lds_bytes, stream>>>(q_s, kt_s, v_s, amask, kpm, ctx, att);
  gemm_k<0><<<gg, 256, 0, stream>>>(ctx, outw, outb, outp, M, EDIM, EDIM, LQ);
}

// Round 5
// 3937.378 us; speedup vs baseline: 1.0949x; 1.0949x over previous
//
#include <hip/hip_runtime.h>

// ApsMultiheadAttention: E=1024 H=16 D=64 L=S=2048 N=2, fp32 throughout.
// Outputs: context (L,N,E) then att (N,L,S), concatenated in d_out.
//
// Round 4 resubmit (round-4 bench never ran: GPU acquisition timeout).
// Change under test vs round 3: attn NT-tile loops FULLY unrolled so all
// per-thread arrays (lg/st4/attacc) are statically indexed -> registers, not
// scratch (rule #20; round-3 counters: WRITE_SIZE 7.3GB, VGPR=64, VALU 10%).
// launch_bounds (1024,2): 256-VGPR budget; occupancy is LDS-limited anyway.

#define EDIM   1024
#define HNUM   16
#define DDIM   64
#define LQ     2048
#define SK     2048
#define NBATCH 2

#define NEG_BIG (-3.0e38f)

// attn tiling
#define RB  8          // q-rows per block
#define ST  256        // s-tile staged in LDS
#define NT  (SK/ST)    // 8 tiles

__device__ __forceinline__ float wave_max_f(float v) {
#pragma unroll
  for (int o = 32; o > 0; o >>= 1) v = fmaxf(v, __shfl_xor(v, o));
  return v;
}
__device__ __forceinline__ float wave_sum_f(float v) {
#pragma unroll
  for (int o = 32; o > 0; o >>= 1) v += __shfl_xor(v, o);
  return v;
}

// ---------------------------------------------------------------------------
// GEMM: C = A(MxK) @ W(NcxK)^T + bias.  Tile 128x128, BK=16, 256 threads,
// 8x8 micro-tile as 2x2 quadrants of 4x4. EPI: 0 plain row-major;
// 1 scatter (N,H,R,D); 2 scatter (N,H,D,R). Rows are (row,n), n fastest.
// (unchanged — validated, ~430us total for all four)
template <int EPI>
__global__ __launch_bounds__(256) void gemm_k(
    const float* __restrict__ A, const float* __restrict__ W,
    const float* __restrict__ bias, float* __restrict__ C,
    const int M, const int K, const int Nc, const int R)
{
  __shared__ float As[16][132];
  __shared__ float Bs[16][132];
  const int t  = threadIdx.x;
  const int m0 = blockIdx.y * 128;
  const int n0 = blockIdx.x * 128;
  const int lr = t >> 2;
  const int lk = (t & 3) << 2;
  const int tx = t & 15;
  const int ty = t >> 4;

  float acc[2][2][4][4];
#pragma unroll
  for (int a = 0; a < 2; ++a)
#pragma unroll
    for (int b = 0; b < 2; ++b)
#pragma unroll
      for (int i = 0; i < 4; ++i)
#pragma unroll
        for (int j = 0; j < 4; ++j) acc[a][b][i][j] = 0.f;

  float4 ra0, ra1, rb0, rb1;
  ra0 = *(const float4*)&A[(size_t)(m0 + lr) * K + lk];
  ra1 = *(const float4*)&A[(size_t)(m0 + lr + 64) * K + lk];
  rb0 = *(const float4*)&W[(size_t)(n0 + lr) * K + lk];
  rb1 = *(const float4*)&W[(size_t)(n0 + lr + 64) * K + lk];

  for (int k0 = 0; k0 < K; k0 += 16) {
    __syncthreads();
    As[lk+0][lr]    = ra0.x; As[lk+1][lr]    = ra0.y; As[lk+2][lr]    = ra0.z; As[lk+3][lr]    = ra0.w;
    As[lk+0][lr+64] = ra1.x; As[lk+1][lr+64] = ra1.y; As[lk+2][lr+64] = ra1.z; As[lk+3][lr+64] = ra1.w;
    Bs[lk+0][lr]    = rb0.x; Bs[lk+1][lr]    = rb0.y; Bs[lk+2][lr]    = rb0.z; Bs[lk+3][lr]    = rb0.w;
    Bs[lk+0][lr+64] = rb1.x; Bs[lk+1][lr+64] = rb1.y; Bs[lk+2][lr+64] = rb1.z; Bs[lk+3][lr+64] = rb1.w;
    __syncthreads();
    const int kn = k0 + 16;
    if (kn < K) {
      ra0 = *(const float4*)&A[(size_t)(m0 + lr) * K + kn + lk];
      ra1 = *(const float4*)&A[(size_t)(m0 + lr + 64) * K + kn + lk];
      rb0 = *(const float4*)&W[(size_t)(n0 + lr) * K + kn + lk];
      rb1 = *(const float4*)&W[(size_t)(n0 + lr + 64) * K + kn + lk];
    }
#pragma unroll
    for (int kk = 0; kk < 16; ++kk) {
      const float4 a0 = *(const float4*)&As[kk][ty * 4];
      const float4 a1 = *(const float4*)&As[kk][ty * 4 + 64];
      const float4 b0 = *(const float4*)&Bs[kk][tx * 4];
      const float4 b1 = *(const float4*)&Bs[kk][tx * 4 + 64];
      const float av[2][4] = {{a0.x,a0.y,a0.z,a0.w},{a1.x,a1.y,a1.z,a1.w}};
      const float bv[2][4] = {{b0.x,b0.y,b0.z,b0.w},{b1.x,b1.y,b1.z,b1.w}};
#pragma unroll
      for (int qi = 0; qi < 2; ++qi)
#pragma unroll
        for (int i = 0; i < 4; ++i)
#pragma unroll
          for (int qj = 0; qj < 2; ++qj)
#pragma unroll
            for (int j = 0; j < 4; ++j)
              acc[qi][qj][i][j] = fmaf(av[qi][i], bv[qj][j], acc[qi][qj][i][j]);
    }
  }

#pragma unroll
  for (int qi = 0; qi < 2; ++qi)
#pragma unroll
    for (int i = 0; i < 4; ++i) {
      const int gr = m0 + qi * 64 + ty * 4 + i;
      const int row = gr / NBATCH;
      const int nb  = gr % NBATCH;
#pragma unroll
      for (int qj = 0; qj < 2; ++qj)
#pragma unroll
        for (int j = 0; j < 4; ++j) {
          const int gc = n0 + qj * 64 + tx * 4 + j;
          const float val = acc[qi][qj][i][j] + bias[gc];
          if constexpr (EPI == 0) {
            C[(size_t)gr * Nc + gc] = val;
          } else {
            const int h = gc >> 6, d = gc & 63;
            if constexpr (EPI == 1)
              C[(((size_t)nb * HNUM + h) * R + row) * DDIM + d] = val;
            else
              C[(((size_t)nb * HNUM + h) * DDIM + d) * (size_t)R + row] = val;
          }
        }
    }
}

// ---------------------------------------------------------------------------
// attn: grid = N*(L/RB) = 512 blocks, 1024 threads (16 waves, 4/SIMD).
// Dynamic LDS (138.2 KB): p[8][2048] | kv[16384] (K tiles then V tiles) |
// q[512] | part[4][8][64] | red[16][2] | m[8] | rinv[8].
//
// Thread maps:
//  A1/A2/att: rows {rr, rr+4} (rr=t>>8), col cc=t&255; slots s=j*256+cc.
//  B2 (PV):   rows {rr, rr+4}, d=t&63, s-quarter sq=(t>>6)&3.
// ALL per-thread arrays statically indexed (tile loops fully unrolled).
__global__ __launch_bounds__(1024, 2) void attn_k(
    const float* __restrict__ qs, const float* __restrict__ kts,
    const float* __restrict__ vs, const float* __restrict__ amask,
    const unsigned char* __restrict__ kpm,
    float* __restrict__ ctx, float* __restrict__ att)
{
  extern __shared__ float lds[];
  float* p_lds = lds;                    // 16384 f
  float* kv    = lds + RB * SK;          // 16384 f
  float* q_lds = kv + 16384;             // 512 f
  float* part  = q_lds + 512;            // 2048 f
  float* red   = part + 2048;            // 32 f
  float* m_l   = red + 32;               // 8 f
  float* ri_l  = m_l + 8;                // 8 f

  const int t    = threadIdx.x;
  const int wg   = blockIdx.x;
  const int n    = wg >> 8;
  const int l0   = (wg & 255) * RB;
  const int wid  = t >> 6;
  const int lane = t & 63;
  const int rr   = t >> 8;        // 0..3 ; rows rr, rr+4
  const int cc   = t & 255;       // A1/A2 col within tile
  const int dd   = t & 63;        // B2 d
  const int sq   = (t >> 6) & 3;  // B2 s-quarter

  float attacc[2][NT];
#pragma unroll
  for (int a = 0; a < 2; ++a)
#pragma unroll
    for (int j = 0; j < NT; ++j) attacc[a][j] = 0.f;

  float4 st4[4];

  for (int h = 0; h < HNUM; ++h) {
    const int nh = n * HNUM + h;
    const float* ktb = kts + (size_t)nh * DDIM * SK;
    const float* vb  = vs  + (size_t)nh * SK * DDIM;

    // ---- stage K tile 0 + Q (loads before barrier: latency hidden) ----
#pragma unroll
    for (int kk = 0; kk < 4; ++kk) {
      const int i4 = t + kk * 1024;
      st4[kk] = *(const float4*)&ktb[(size_t)(i4 >> 6) * SK + ((i4 & 63) << 2)];
    }
    float4 qv4;
    if (t < 128) qv4 = ((const float4*)(qs + ((size_t)nh * LQ + l0) * DDIM))[t];
    __syncthreads();  // prev head fully done with kv/part
#pragma unroll
    for (int kk = 0; kk < 4; ++kk) ((float4*)kv)[t + kk * 1024] = st4[kk];
    if (t < 128) ((float4*)q_lds)[t] = qv4;
    __syncthreads();

    // ---- A1: logits (regs) + row max. kv = K tile [d][s] ----
    float lg[2][NT];
    float rmax0 = NEG_BIG, rmax1 = NEG_BIG;
    const float* qrow0 = q_lds + rr * DDIM;
    const float* qrow1 = q_lds + (rr + 4) * DDIM;

#pragma unroll
    for (int j = 0; j < NT; ++j) {
      if (j < NT - 1) {  // prefetch next K tile into regs
#pragma unroll
        for (int kk = 0; kk < 4; ++kk) {
          const int i4 = t + kk * 1024;
          st4[kk] = *(const float4*)&ktb[(size_t)(i4 >> 6) * SK + (j + 1) * ST + ((i4 & 63) << 2)];
        }
      }
      float a0 = 0.f, b0 = 0.f, a1 = 0.f, b1 = 0.f;
#pragma unroll
      for (int d4 = 0; d4 < DDIM; d4 += 4) {
        const float4 q0 = *(const float4*)&qrow0[d4];
        const float4 q1 = *(const float4*)&qrow1[d4];
        const float k0 = kv[(d4 + 0) * ST + cc];
        const float k1 = kv[(d4 + 1) * ST + cc];
        const float k2 = kv[(d4 + 2) * ST + cc];
        const float k3 = kv[(d4 + 3) * ST + cc];
        a0 = fmaf(q0.x, k0, a0); b0 = fmaf(q0.y, k1, b0);
        a0 = fmaf(q0.z, k2, a0); b0 = fmaf(q0.w, k3, b0);
        a1 = fmaf(q1.x, k0, a1); b1 = fmaf(q1.y, k1, b1);
        a1 = fmaf(q1.z, k2, a1); b1 = fmaf(q1.w, k3, b1);
      }
      const int s = j * ST + cc;
      const bool kill = (kpm[n * SK + s] != 0);
      float l0v = (a0 + b0) * 0.125f + amask[(size_t)(l0 + rr) * SK + s];
      float l1v = (a1 + b1) * 0.125f + amask[(size_t)(l0 + rr + 4) * SK + s];
      if (kill) { l0v = NEG_BIG; l1v = NEG_BIG; }
      lg[0][j] = l0v; lg[1][j] = l1v;
      rmax0 = fmaxf(rmax0, l0v); rmax1 = fmaxf(rmax1, l1v);
      __syncthreads();  // all reads of kv tile j done
      if (j < NT - 1) {
#pragma unroll
        for (int kk = 0; kk < 4; ++kk) ((float4*)kv)[t + kk * 1024] = st4[kk];
        __syncthreads();
      }
    }

    // row max: wave w covers rows (w>>2) and (w>>2)+4
    rmax0 = wave_max_f(rmax0); rmax1 = wave_max_f(rmax1);
    if (lane == 0) { red[wid * 2] = rmax0; red[wid * 2 + 1] = rmax1; }
    __syncthreads();
    if (t < RB) {
      const int g = t & 3, ix = t >> 2;
      float m = red[(4 * g) * 2 + ix];
#pragma unroll
      for (int w = 1; w < 4; ++w) m = fmaxf(m, red[(4 * g + w) * 2 + ix]);
      m_l[t] = m;
    }
    __syncthreads();

    // ---- A2: p = exp(lg - m) -> p_lds + regs; row sums -> rinv ----
    const float mm0 = m_l[rr], mm1 = m_l[rr + 4];
    float sum0 = 0.f, sum1 = 0.f;
#pragma unroll
    for (int j = 0; j < NT; ++j) {
      const float p0 = __expf(lg[0][j] - mm0);
      const float p1 = __expf(lg[1][j] - mm1);
      lg[0][j] = p0; lg[1][j] = p1;         // reuse regs as p
      sum0 += p0; sum1 += p1;
      p_lds[rr * SK + j * ST + cc]       = p0;
      p_lds[(rr + 4) * SK + j * ST + cc] = p1;
    }
    sum0 = wave_sum_f(sum0); sum1 = wave_sum_f(sum1);
    if (lane == 0) { red[wid * 2] = sum0; red[wid * 2 + 1] = sum1; }
    __syncthreads();
    if (t < RB) {
      const int g = t & 3, ix = t >> 2;
      float ssum = 0.f;
#pragma unroll
      for (int w = 0; w < 4; ++w) ssum += red[(4 * g + w) * 2 + ix];
      ri_l[t] = 1.0f / ssum;
    }
    __syncthreads();
    const float ri0 = ri_l[rr], ri1 = ri_l[rr + 4];
#pragma unroll
    for (int j = 0; j < NT; ++j) {
      attacc[0][j] = fmaf(lg[0][j], ri0, attacc[0][j]);
      attacc[1][j] = fmaf(lg[1][j], ri1, attacc[1][j]);
    }

    // ---- B2: PV. kv reused as V tile [s][d] ----
#pragma unroll
    for (int kk = 0; kk < 4; ++kk) {
      const int i4 = t + kk * 1024;
      st4[kk] = *(const float4*)&vb[(size_t)(i4 >> 4) * DDIM + ((i4 & 15) << 2)];
    }
    // kv readers (A1) are all past barriers; safe to overwrite
#pragma unroll
    for (int kk = 0; kk < 4; ++kk) ((float4*)kv)[t + kk * 1024] = st4[kk];
    __syncthreads();

    float ca00 = 0.f, ca01 = 0.f, ca10 = 0.f, ca11 = 0.f;
#pragma unroll
    for (int j = 0; j < NT; ++j) {
      if (j < NT - 1) {  // prefetch next V tile
#pragma unroll
        for (int kk = 0; kk < 4; ++kk) {
          const int i4 = t + kk * 1024;
          st4[kk] = *(const float4*)&vb[(size_t)((j + 1) * ST + (i4 >> 4)) * DDIM + ((i4 & 15) << 2)];
        }
      }
      const int sb = sq * 64;
      const float* p0r = p_lds + rr * SK + j * ST + sb;
      const float* p1r = p_lds + (rr + 4) * SK + j * ST + sb;
#pragma unroll
      for (int s2 = 0; s2 < 64; s2 += 4) {
        const float4 p0 = *(const float4*)&p0r[s2];   // wave-uniform broadcast
        const float4 p1 = *(const float4*)&p1r[s2];
        const float v0 = kv[(sb + s2 + 0) * DDIM + dd];
        const float v1 = kv[(sb + s2 + 1) * DDIM + dd];
        const float v2 = kv[(sb + s2 + 2) * DDIM + dd];
        const float v3 = kv[(sb + s2 + 3) * DDIM + dd];
        ca00 = fmaf(p0.x, v0, ca00); ca01 = fmaf(p0.y, v1, ca01);
        ca00 = fmaf(p0.z, v2, ca00); ca01 = fmaf(p0.w, v3, ca01);
        ca10 = fmaf(p1.x, v0, ca10); ca11 = fmaf(p1.y, v1, ca11);
        ca10 = fmaf(p1.z, v2, ca10); ca11 = fmaf(p1.w, v3, ca11);
      }
      __syncthreads();
      if (j < NT - 1) {
#pragma unroll
        for (int kk = 0; kk < 4; ++kk) ((float4*)kv)[t + kk * 1024] = st4[kk];
        __syncthreads();
      }
    }
    part[(sq * RB + rr) * DDIM + dd]     = ca00 + ca01;
    part[(sq * RB + rr + 4) * DDIM + dd] = ca10 + ca11;
    __syncthreads();
    if (t < RB * DDIM) {  // 512 threads write ctx
      const int r = t >> 6, d = t & 63;
      float sv = 0.f;
#pragma unroll
      for (int q2 = 0; q2 < 4; ++q2) sv += part[(q2 * RB + r) * DDIM + d];
      ctx[((size_t)(l0 + r) * NBATCH + n) * EDIM + h * DDIM + d] = sv * ri_l[r];
    }
    // next head's first barrier protects part/kv reuse
  }

  // ---- final att write (one pass) ----
  const float c16 = 1.0f / (float)HNUM;
#pragma unroll
  for (int j = 0; j < NT; ++j) {
    att[((size_t)n * LQ + l0 + rr) * SK + j * ST + cc]     = attacc[0][j] * c16;
    att[((size_t)n * LQ + l0 + rr + 4) * SK + j * ST + cc] = attacc[1][j] * c16;
  }
}

// ---------------------------------------------------------------------------
extern "C" void kernel_launch(void* const* d_in, const int* in_sizes, int n_in,
                              void* d_out, int out_size, void* d_ws, size_t ws_size,
                              hipStream_t stream)
{
  const float*         query = (const float*)d_in[0];
  const float*         key   = (const float*)d_in[1];
  const float*         value = (const float*)d_in[2];
  const unsigned char* kpm   = (const unsigned char*)d_in[3];
  const float*         amask = (const float*)d_in[4];
  const float*         ipw   = (const float*)d_in[5];
  const float*         ipb   = (const float*)d_in[6];
  const float*         outw  = (const float*)d_in[7];
  const float*         outb  = (const float*)d_in[8];

  float* outp = (float*)d_out;                          // context (L,N,E)
  float* att  = outp + (size_t)LQ * NBATCH * EDIM;      // att (N,L,S)

  // workspace: q_s 16MB | kt_s 16MB | v_s 16MB | ctx 16MB
  const size_t nQ = (size_t)NBATCH * HNUM * LQ * DDIM;
  const size_t needed = (3 * nQ + (size_t)LQ * NBATCH * EDIM) * 4;
  if (ws_size < needed) return;

  float* ws   = (float*)d_ws;
  float* q_s  = ws;
  float* kt_s = q_s  + nQ;
  float* v_s  = kt_s + nQ;
  float* ctx  = v_s  + nQ;

  const int M = LQ * NBATCH;
  dim3 gg(EDIM / 128, M / 128);

  const int lds_bytes = (RB * SK + 16384 + 512 + 2048 + 32 + 8 + 8) * 4;  // 141504
  (void)hipFuncSetAttribute((const void*)attn_k,
                            hipFuncAttributeMaxDynamicSharedMemorySize, lds_bytes);

  gemm_k<1><<<gg, 256, 0, stream>>>(query, ipw,                   ipb,            q_s,  M, EDIM, EDIM, LQ);
  gemm_k<2><<<gg, 256, 0, stream>>>(key,   ipw + EDIM * EDIM,     ipb + EDIM,     kt_s, M, EDIM, EDIM, SK);
  gemm_k<1><<<gg, 256, 0, stream>>>(value, ipw + 2 * EDIM * EDIM, ipb + 2 * EDIM, v_s,  M, EDIM, EDIM, SK);
  attn_k<<<NBATCH * (LQ / RB), 1024, lds_bytes, stream>>>(q_s, kt_s, v_s, amask, kpm, ctx, att);
  gemm_k<0><<<gg, 256, 0, stream>>>(ctx, outw, outb, outp, M, EDIM, EDIM, LQ);
}

// Round 6
// 2189.387 us; speedup vs baseline: 1.9691x; 1.7984x over previous
//
#include <hip/hip_runtime.h>

// ApsMultiheadAttention: E=1024 H=16 D=64 L=S=2048 N=2, fp32 throughout.
// Outputs: context (L,N,E) then att (N,L,S), concatenated in d_out.
//
// Round 5 -> 6: attn was spilling ~30 VGPRs/thread (VGPR=64 budget from the
// backend occupancy heuristic, which can't see the 141KB *dynamic* LDS and
// targets 8 waves/EU; WRITE_SIZE 6.9GB of scratch). Fixes:
//  1) amdgpu_waves_per_eu(4,4): LDS caps us at 1 block/CU = 4 waves/EU, so
//     legalize the 128-VGPR budget.
//  2) Demand cut below 64 anyway: logits go straight to p_lds (no lg[2][8]),
//     prefetch uses named pf0..pf3 (no st4[]), attacc split into attA/attB.

#define EDIM   1024
#define HNUM   16
#define DDIM   64
#define LQ     2048
#define SK     2048
#define NBATCH 2

#define NEG_BIG (-3.0e38f)

// attn tiling
#define RB  8          // q-rows per block
#define ST  256        // s-tile staged in LDS
#define NT  (SK/ST)    // 8 tiles

__device__ __forceinline__ float wave_max_f(float v) {
#pragma unroll
  for (int o = 32; o > 0; o >>= 1) v = fmaxf(v, __shfl_xor(v, o));
  return v;
}
__device__ __forceinline__ float wave_sum_f(float v) {
#pragma unroll
  for (int o = 32; o > 0; o >>= 1) v += __shfl_xor(v, o);
  return v;
}

// ---------------------------------------------------------------------------
// GEMM: C = A(MxK) @ W(NcxK)^T + bias.  Tile 128x128, BK=16, 256 threads,
// 8x8 micro-tile as 2x2 quadrants of 4x4. EPI: 0 plain row-major;
// 1 scatter (N,H,R,D); 2 scatter (N,H,D,R). Rows are (row,n), n fastest.
// (unchanged — validated)
template <int EPI>
__global__ __launch_bounds__(256) void gemm_k(
    const float* __restrict__ A, const float* __restrict__ W,
    const float* __restrict__ bias, float* __restrict__ C,
    const int M, const int K, const int Nc, const int R)
{
  __shared__ float As[16][132];
  __shared__ float Bs[16][132];
  const int t  = threadIdx.x;
  const int m0 = blockIdx.y * 128;
  const int n0 = blockIdx.x * 128;
  const int lr = t >> 2;
  const int lk = (t & 3) << 2;
  const int tx = t & 15;
  const int ty = t >> 4;

  float acc[2][2][4][4];
#pragma unroll
  for (int a = 0; a < 2; ++a)
#pragma unroll
    for (int b = 0; b < 2; ++b)
#pragma unroll
      for (int i = 0; i < 4; ++i)
#pragma unroll
        for (int j = 0; j < 4; ++j) acc[a][b][i][j] = 0.f;

  float4 ra0, ra1, rb0, rb1;
  ra0 = *(const float4*)&A[(size_t)(m0 + lr) * K + lk];
  ra1 = *(const float4*)&A[(size_t)(m0 + lr + 64) * K + lk];
  rb0 = *(const float4*)&W[(size_t)(n0 + lr) * K + lk];
  rb1 = *(const float4*)&W[(size_t)(n0 + lr + 64) * K + lk];

  for (int k0 = 0; k0 < K; k0 += 16) {
    __syncthreads();
    As[lk+0][lr]    = ra0.x; As[lk+1][lr]    = ra0.y; As[lk+2][lr]    = ra0.z; As[lk+3][lr]    = ra0.w;
    As[lk+0][lr+64] = ra1.x; As[lk+1][lr+64] = ra1.y; As[lk+2][lr+64] = ra1.z; As[lk+3][lr+64] = ra1.w;
    Bs[lk+0][lr]    = rb0.x; Bs[lk+1][lr]    = rb0.y; Bs[lk+2][lr]    = rb0.z; Bs[lk+3][lr]    = rb0.w;
    Bs[lk+0][lr+64] = rb1.x; Bs[lk+1][lr+64] = rb1.y; Bs[lk+2][lr+64] = rb1.z; Bs[lk+3][lr+64] = rb1.w;
    __syncthreads();
    const int kn = k0 + 16;
    if (kn < K) {
      ra0 = *(const float4*)&A[(size_t)(m0 + lr) * K + kn + lk];
      ra1 = *(const float4*)&A[(size_t)(m0 + lr + 64) * K + kn + lk];
      rb0 = *(const float4*)&W[(size_t)(n0 + lr) * K + kn + lk];
      rb1 = *(const float4*)&W[(size_t)(n0 + lr + 64) * K + kn + lk];
    }
#pragma unroll
    for (int kk = 0; kk < 16; ++kk) {
      const float4 a0 = *(const float4*)&As[kk][ty * 4];
      const float4 a1 = *(const float4*)&As[kk][ty * 4 + 64];
      const float4 b0 = *(const float4*)&Bs[kk][tx * 4];
      const float4 b1 = *(const float4*)&Bs[kk][tx * 4 + 64];
      const float av[2][4] = {{a0.x,a0.y,a0.z,a0.w},{a1.x,a1.y,a1.z,a1.w}};
      const float bv[2][4] = {{b0.x,b0.y,b0.z,b0.w},{b1.x,b1.y,b1.z,b1.w}};
#pragma unroll
      for (int qi = 0; qi < 2; ++qi)
#pragma unroll
        for (int i = 0; i < 4; ++i)
#pragma unroll
          for (int qj = 0; qj < 2; ++qj)
#pragma unroll
            for (int j = 0; j < 4; ++j)
              acc[qi][qj][i][j] = fmaf(av[qi][i], bv[qj][j], acc[qi][qj][i][j]);
    }
  }

#pragma unroll
  for (int qi = 0; qi < 2; ++qi)
#pragma unroll
    for (int i = 0; i < 4; ++i) {
      const int gr = m0 + qi * 64 + ty * 4 + i;
      const int row = gr / NBATCH;
      const int nb  = gr % NBATCH;
#pragma unroll
      for (int qj = 0; qj < 2; ++qj)
#pragma unroll
        for (int j = 0; j < 4; ++j) {
          const int gc = n0 + qj * 64 + tx * 4 + j;
          const float val = acc[qi][qj][i][j] + bias[gc];
          if constexpr (EPI == 0) {
            C[(size_t)gr * Nc + gc] = val;
          } else {
            const int h = gc >> 6, d = gc & 63;
            if constexpr (EPI == 1)
              C[(((size_t)nb * HNUM + h) * R + row) * DDIM + d] = val;
            else
              C[(((size_t)nb * HNUM + h) * DDIM + d) * (size_t)R + row] = val;
          }
        }
    }
}

// ---------------------------------------------------------------------------
// attn: grid = N*(L/RB) = 512 blocks, 1024 threads (16 waves; LDS-bound to
// 1 block/CU = 4 waves/EU, pinned via amdgpu_waves_per_eu(4,4)).
// Dynamic LDS (138.2 KB): p[8][2048] | kv[16384] (K tiles then V tiles) |
// q[512] | part[4][8][64] | red[16][2] | m[8] | rinv[8].
//
// Thread maps:
//  A1/A2/att: rows {rr, rr+4} (rr=t>>8), col cc=t&255; slots s=j*256+cc.
//  B2 (PV):   rows {rr, rr+4}, d=t&63, s-quarter sq=(t>>6)&3.
// Logits live in p_lds (not registers); prefetch in named pf0..pf3.
__global__ __launch_bounds__(1024) __attribute__((amdgpu_waves_per_eu(4, 4)))
void attn_k(
    const float* __restrict__ qs, const float* __restrict__ kts,
    const float* __restrict__ vs, const float* __restrict__ amask,
    const unsigned char* __restrict__ kpm,
    float* __restrict__ ctx, float* __restrict__ att)
{
  extern __shared__ float lds[];
  float* p_lds = lds;                    // 16384 f
  float* kv    = lds + RB * SK;          // 16384 f
  float* q_lds = kv + 16384;             // 512 f
  float* part  = q_lds + 512;            // 2048 f
  float* red   = part + 2048;            // 32 f
  float* m_l   = red + 32;               // 8 f
  float* ri_l  = m_l + 8;                // 8 f

  const int t    = threadIdx.x;
  const int wg   = blockIdx.x;
  const int n    = wg >> 8;
  const int l0   = (wg & 255) * RB;
  const int wid  = t >> 6;
  const int lane = t & 63;
  const int rr   = t >> 8;        // 0..3 ; rows rr, rr+4
  const int cc   = t & 255;       // A1/A2 col within tile
  const int dd   = t & 63;        // B2 d
  const int sq   = (t >> 6) & 3;  // B2 s-quarter

  float attA[NT], attB[NT];
#pragma unroll
  for (int j = 0; j < NT; ++j) { attA[j] = 0.f; attB[j] = 0.f; }

  for (int h = 0; h < HNUM; ++h) {
    const int nh = n * HNUM + h;
    const float* ktb = kts + (size_t)nh * DDIM * SK;
    const float* vb  = vs  + (size_t)nh * SK * DDIM;

    auto kload = [&](int kk, int jj) -> float4 {
      const int i4 = t + kk * 1024;
      return *(const float4*)&ktb[(size_t)(i4 >> 6) * SK + jj * ST + ((i4 & 63) << 2)];
    };
    auto vload = [&](int kk, int jj) -> float4 {
      const int i4 = t + kk * 1024;
      return *(const float4*)&vb[(size_t)(jj * ST + (i4 >> 4)) * DDIM + ((i4 & 15) << 2)];
    };

    // ---- stage K tile 0 + Q (loads before barrier: latency hidden) ----
    float4 pf0 = kload(0, 0), pf1 = kload(1, 0), pf2 = kload(2, 0), pf3 = kload(3, 0);
    float4 qv4;
    if (t < 128) qv4 = ((const float4*)(qs + ((size_t)nh * LQ + l0) * DDIM))[t];
    __syncthreads();  // prev head fully done with kv/part
    ((float4*)kv)[t]        = pf0;
    ((float4*)kv)[t + 1024] = pf1;
    ((float4*)kv)[t + 2048] = pf2;
    ((float4*)kv)[t + 3072] = pf3;
    if (t < 128) ((float4*)q_lds)[t] = qv4;
    __syncthreads();

    // ---- A1: logits -> p_lds + row max. kv = K tile [d][s] ----
    float rmax0 = NEG_BIG, rmax1 = NEG_BIG;
    const float* qrow0 = q_lds + rr * DDIM;
    const float* qrow1 = q_lds + (rr + 4) * DDIM;

#pragma unroll
    for (int j = 0; j < NT; ++j) {
      if (j < NT - 1) {  // prefetch next K tile into named regs
        pf0 = kload(0, j + 1); pf1 = kload(1, j + 1);
        pf2 = kload(2, j + 1); pf3 = kload(3, j + 1);
      }
      float a0 = 0.f, b0 = 0.f, a1 = 0.f, b1 = 0.f;
#pragma unroll
      for (int d4 = 0; d4 < DDIM; d4 += 4) {
        const float4 q0 = *(const float4*)&qrow0[d4];
        const float4 q1 = *(const float4*)&qrow1[d4];
        const float k0 = kv[(d4 + 0) * ST + cc];
        const float k1 = kv[(d4 + 1) * ST + cc];
        const float k2 = kv[(d4 + 2) * ST + cc];
        const float k3 = kv[(d4 + 3) * ST + cc];
        a0 = fmaf(q0.x, k0, a0); b0 = fmaf(q0.y, k1, b0);
        a0 = fmaf(q0.z, k2, a0); b0 = fmaf(q0.w, k3, b0);
        a1 = fmaf(q1.x, k0, a1); b1 = fmaf(q1.y, k1, b1);
        a1 = fmaf(q1.z, k2, a1); b1 = fmaf(q1.w, k3, b1);
      }
      const int s = j * ST + cc;
      const bool kill = (kpm[n * SK + s] != 0);
      float l0v = (a0 + b0) * 0.125f + amask[(size_t)(l0 + rr) * SK + s];
      float l1v = (a1 + b1) * 0.125f + amask[(size_t)(l0 + rr + 4) * SK + s];
      if (kill) { l0v = NEG_BIG; l1v = NEG_BIG; }
      p_lds[(size_t)rr * SK + s]       = l0v;   // logits to LDS, not regs
      p_lds[(size_t)(rr + 4) * SK + s] = l1v;
      rmax0 = fmaxf(rmax0, l0v); rmax1 = fmaxf(rmax1, l1v);
      __syncthreads();  // all reads of kv tile j done
      if (j < NT - 1) {
        ((float4*)kv)[t]        = pf0;
        ((float4*)kv)[t + 1024] = pf1;
        ((float4*)kv)[t + 2048] = pf2;
        ((float4*)kv)[t + 3072] = pf3;
        __syncthreads();
      }
    }

    // row max: wave w covers rows (w>>2) and (w>>2)+4
    rmax0 = wave_max_f(rmax0); rmax1 = wave_max_f(rmax1);
    if (lane == 0) { red[wid * 2] = rmax0; red[wid * 2 + 1] = rmax1; }
    __syncthreads();
    if (t < RB) {
      const int g = t & 3, ix = t >> 2;
      float m = red[(4 * g) * 2 + ix];
#pragma unroll
      for (int w = 1; w < 4; ++w) m = fmaxf(m, red[(4 * g + w) * 2 + ix]);
      m_l[t] = m;
    }
    __syncthreads();

    // ---- A2: p = exp(logit - m) in p_lds; row sums -> rinv ----
    const float mm0 = m_l[rr], mm1 = m_l[rr + 4];
    float sum0 = 0.f, sum1 = 0.f;
#pragma unroll
    for (int j = 0; j < NT; ++j) {
      const int s = j * ST + cc;
      const float p0 = __expf(p_lds[(size_t)rr * SK + s] - mm0);
      const float p1 = __expf(p_lds[(size_t)(rr + 4) * SK + s] - mm1);
      p_lds[(size_t)rr * SK + s]       = p0;
      p_lds[(size_t)(rr + 4) * SK + s] = p1;
      sum0 += p0; sum1 += p1;
    }
    sum0 = wave_sum_f(sum0); sum1 = wave_sum_f(sum1);
    if (lane == 0) { red[wid * 2] = sum0; red[wid * 2 + 1] = sum1; }
    __syncthreads();
    if (t < RB) {
      const int g = t & 3, ix = t >> 2;
      float ssum = 0.f;
#pragma unroll
      for (int w = 0; w < 4; ++w) ssum += red[(4 * g + w) * 2 + ix];
      ri_l[t] = 1.0f / ssum;
    }
    __syncthreads();

    // ---- att accumulation (reads own p slots back from LDS) ----
    const float ri0 = ri_l[rr], ri1 = ri_l[rr + 4];
#pragma unroll
    for (int j = 0; j < NT; ++j) {
      const int s = j * ST + cc;
      attA[j] = fmaf(p_lds[(size_t)rr * SK + s],       ri0, attA[j]);
      attB[j] = fmaf(p_lds[(size_t)(rr + 4) * SK + s], ri1, attB[j]);
    }

    // ---- B2: PV. kv reused as V tile [s][d] ----
    pf0 = vload(0, 0); pf1 = vload(1, 0); pf2 = vload(2, 0); pf3 = vload(3, 0);
    // kv readers (A1) are all past the reduction barriers; safe to overwrite
    ((float4*)kv)[t]        = pf0;
    ((float4*)kv)[t + 1024] = pf1;
    ((float4*)kv)[t + 2048] = pf2;
    ((float4*)kv)[t + 3072] = pf3;
    __syncthreads();

    float ca00 = 0.f, ca01 = 0.f, ca10 = 0.f, ca11 = 0.f;
#pragma unroll
    for (int j = 0; j < NT; ++j) {
      if (j < NT - 1) {  // prefetch next V tile
        pf0 = vload(0, j + 1); pf1 = vload(1, j + 1);
        pf2 = vload(2, j + 1); pf3 = vload(3, j + 1);
      }
      const int sb = sq * 64;
      const float* p0r = p_lds + (size_t)rr * SK + j * ST + sb;
      const float* p1r = p_lds + (size_t)(rr + 4) * SK + j * ST + sb;
#pragma unroll
      for (int s2 = 0; s2 < 64; s2 += 4) {
        const float4 p0 = *(const float4*)&p0r[s2];   // wave-uniform broadcast
        const float4 p1 = *(const float4*)&p1r[s2];
        const float v0 = kv[(sb + s2 + 0) * DDIM + dd];
        const float v1 = kv[(sb + s2 + 1) * DDIM + dd];
        const float v2 = kv[(sb + s2 + 2) * DDIM + dd];
        const float v3 = kv[(sb + s2 + 3) * DDIM + dd];
        ca00 = fmaf(p0.x, v0, ca00); ca01 = fmaf(p0.y, v1, ca01);
        ca00 = fmaf(p0.z, v2, ca00); ca01 = fmaf(p0.w, v3, ca01);
        ca10 = fmaf(p1.x, v0, ca10); ca11 = fmaf(p1.y, v1, ca11);
        ca10 = fmaf(p1.z, v2, ca10); ca11 = fmaf(p1.w, v3, ca11);
      }
      __syncthreads();
      if (j < NT - 1) {
        ((float4*)kv)[t]        = pf0;
        ((float4*)kv)[t + 1024] = pf1;
        ((float4*)kv)[t + 2048] = pf2;
        ((float4*)kv)[t + 3072] = pf3;
        __syncthreads();
      }
    }
    part[(sq * RB + rr) * DDIM + dd]     = ca00 + ca01;
    part[(sq * RB + rr + 4) * DDIM + dd] = ca10 + ca11;
    __syncthreads();
    if (t < RB * DDIM) {  // 512 threads write ctx
      const int r = t >> 6, d = t & 63;
      float sv = 0.f;
#pragma unroll
      for (int q2 = 0; q2 < 4; ++q2) sv += part[(q2 * RB + r) * DDIM + d];
      ctx[((size_t)(l0 + r) * NBATCH + n) * EDIM + h * DDIM + d] = sv * ri_l[r];
    }
    // next head's first barrier protects part/kv reuse
  }

  // ---- final att write (one pass) ----
  const float c16 = 1.0f / (float)HNUM;
#pragma unroll
  for (int j = 0; j < NT; ++j) {
    att[((size_t)n * LQ + l0 + rr) * SK + j * ST + cc]     = attA[j] * c16;
    att[((size_t)n * LQ + l0 + rr + 4) * SK + j * ST + cc] = attB[j] * c16;
  }
}

// ---------------------------------------------------------------------------
extern "C" void kernel_launch(void* const* d_in, const int* in_sizes, int n_in,
                              void* d_out, int out_size, void* d_ws, size_t ws_size,
                              hipStream_t stream)
{
  const float*         query = (const float*)d_in[0];
  const float*         key   = (const float*)d_in[1];
  const float*         value = (const float*)d_in[2];
  const unsigned char* kpm   = (const unsigned char*)d_in[3];
  const float*         amask = (const float*)d_in[4];
  const float*         ipw   = (const float*)d_in[5];
  const float*         ipb   = (const float*)d_in[6];
  const float*         outw  = (const float*)d_in[7];
  const float*         outb  = (const float*)d_in[8];

  float* outp = (float*)d_out;                          // context (L,N,E)
  float* att  = outp + (size_t)LQ * NBATCH * EDIM;      // att (N,L,S)

  // workspace: q_s 16MB | kt_s 16MB | v_s 16MB | ctx 16MB
  const size_t nQ = (size_t)NBATCH * HNUM * LQ * DDIM;
  const size_t needed = (3 * nQ + (size_t)LQ * NBATCH * EDIM) * 4;
  if (ws_size < needed) return;

  float* ws   = (float*)d_ws;
  float* q_s  = ws;
  float* kt_s = q_s  + nQ;
  float* v_s  = kt_s + nQ;
  float* ctx  = v_s  + nQ;

  const int M = LQ * NBATCH;
  dim3 gg(EDIM / 128, M / 128);

  const int lds_bytes = (RB * SK + 16384 + 512 + 2048 + 32 + 8 + 8) * 4;  // 141504
  (void)hipFuncSetAttribute((const void*)attn_k,
                            hipFuncAttributeMaxDynamicSharedMemorySize, lds_bytes);

  gemm_k<1><<<gg, 256, 0, stream>>>(query, ipw,                   ipb,            q_s,  M, EDIM, EDIM, LQ);
  gemm_k<2><<<gg, 256, 0, stream>>>(key,   ipw + EDIM * EDIM,     ipb + EDIM,     kt_s, M, EDIM, EDIM, SK);
  gemm_k<1><<<gg, 256, 0, stream>>>(value, ipw + 2 * EDIM * EDIM, ipb + 2 * EDIM, v_s,  M, EDIM, EDIM, SK);
  attn_k<<<NBATCH * (LQ / RB), 1024, lds_bytes, stream>>>(q_s, kt_s, v_s, amask, kpm, ctx, att);
  gemm_k<0><<<gg, 256, 0, stream>>>(ctx, outw, outb, outp, M, EDIM, EDIM, LQ);
}